// Round 6
// baseline (413.483 us; speedup 1.0000x reference)
//
#include <hip/hip_runtime.h>
#include <hip/hip_bf16.h>
#include <stdint.h>

// Problem constants
#define H2      1024
#define SEQ     512
#define BATCH   64
#define M_TOTAL (SEQ * BATCH)   // 32768 rows, row m = s*64 + b (enc layout (S,B,H2))

typedef __attribute__((ext_vector_type(8))) short short8;  // 8 bf16 (4 VGPRs)
typedef __attribute__((ext_vector_type(4))) float f32x4;   // mfma acc

__device__ __forceinline__ unsigned pack2_bf16(float lo, float hi) {
    union { __hip_bfloat162 h; unsigned u; } v;
    v.h = __float22bfloat162_rn(make_float2(lo, hi));
    return v.u;
}

__device__ __forceinline__ float fast_tanh(float x) {
    float e = __expf(2.0f * x);
    return __fdividef(e - 1.0f, e + 1.0f);
}

// Async global->LDS, 16B per lane; LDS dest = wave-uniform base + lane*16B.
__device__ __forceinline__ void gl_lds16(const unsigned short* g, unsigned short* l) {
    __builtin_amdgcn_global_load_lds(
        (const __attribute__((address_space(1))) unsigned int*)g,
        (__attribute__((address_space(3))) unsigned int*)l, 16, 0, 0);
}

// Swizzled W1e layout (MFMA-fragment-major):
//   region gr = RB*32 + KC  (RB = h>>4, KC = k>>5), 512 shorts each.
//   chunk L in [0,64): 8 shorts = (h = RB*16 + (L&15), k = KC*32 + (L>>4)*8).
// k_energy glds reads base + lane*16B: 1KB contiguous per instr, and the LDS
// image is exactly MFMA fragment order (zero bank conflicts).

// ------------------------------------------------------------------
// k_setup: fused prep. Block ranges:
//   [0,512)   : W1 enc-slice -> bf16 W1e (swizzled), 4 regions/block
//   [512,640) : zero logits (32768)
//   [640,704) : state projection sp[b][h] = sum_k st*W1 + b1 (both layers)
__global__ __launch_bounds__(256) void k_setup(const float* __restrict__ W1,
                                               const float* __restrict__ b1,
                                               const float* __restrict__ state,
                                               unsigned short* __restrict__ W1e,
                                               float* __restrict__ logits,
                                               float* __restrict__ sp) {
    int blk = blockIdx.x, tid = threadIdx.x;
    int lane = tid & 63;
    if (blk < 512) {
        // ---- W1e swizzled prep: wave w -> region blk*4+w ----
        int gr = blk * 4 + (tid >> 6);
        int L  = ((lane & 3) << 4) | (lane >> 2);   // read-coalescing perm
        int h  = ((gr >> 5) << 4) + (L & 15);
        int k  = ((gr & 31) << 5) + ((L >> 4) << 3);
        const float* src = W1 + (size_t)h * 3072 + 2048 + k;
        float4 v0 = *(const float4*)(src);
        float4 v1 = *(const float4*)(src + 4);
        uint4 o;
        o.x = pack2_bf16(v0.x, v0.y); o.y = pack2_bf16(v0.z, v0.w);
        o.z = pack2_bf16(v1.x, v1.y); o.w = pack2_bf16(v1.z, v1.w);
        *(uint4*)(W1e + (size_t)gr * 512 + L * 8) = o;
    } else if (blk < 640) {
        logits[(blk - 512) * 256 + tid] = 0.f;
    } else {
        // ---- state projection: mT = blk-640 (16 h-rows), all 64 b, K=2048 ----
        int mT   = blk - 640;
        int wave = tid >> 6;                // b-tile 0..3
        int c    = lane & 15;
        int kq   = (lane >> 4) << 3;
        int h    = mT * 16 + c;
        int b    = wave * 16 + c;
        const float* ap = W1 + (size_t)h * 3072 + kq;   // state cols [0,2048)
        f32x4 acc = {0.f, 0.f, 0.f, 0.f};
        #pragma unroll 4
        for (int k0 = 0; k0 < 2048; k0 += 32) {
            int k = k0 + kq;
            float4 a0 = *(const float4*)(ap + k0);
            float4 a1 = *(const float4*)(ap + k0 + 4);
            int l = k >> 10, j = k & 1023;
            const float* bp = state + (((size_t)l * 64 + b) << 10) + j;
            float4 b0 = *(const float4*)bp;
            float4 b1v = *(const float4*)(bp + 4);
            union { short8 s; uint4 u; } fa, fb;
            fa.u.x = pack2_bf16(a0.x, a0.y); fa.u.y = pack2_bf16(a0.z, a0.w);
            fa.u.z = pack2_bf16(a1.x, a1.y); fa.u.w = pack2_bf16(a1.z, a1.w);
            fb.u.x = pack2_bf16(b0.x, b0.y); fb.u.y = pack2_bf16(b0.z, b0.w);
            fb.u.z = pack2_bf16(b1v.x, b1v.y); fb.u.w = pack2_bf16(b1v.z, b1v.w);
            acc = __builtin_amdgcn_mfma_f32_16x16x32_bf16(fa.s, fb.s, acc, 0, 0, 0);
        }
        int quad = lane >> 4;
        int bcol = wave * 16 + c;
        #pragma unroll
        for (int i = 0; i < 4; ++i) {
            int hh = mT * 16 + quad * 4 + i;
            sp[((size_t)bcol << 10) + hh] = acc[i] + b1[hh];
        }
    }
}

// ------------------------------------------------------------------
// k_energy: C(32768,1024) = enc(fp32->bf16 in-reg) @ W1e^T, fused epilogue:
// logit[m] += sum_h tanh(C[m,h] + sp[b,h]) * W2[h],  b = m & 63.
// A: global fp32 load -> pack -> ds_write_b128 into fragment-order regions
//    (write pattern is 2-way bank aliasing = free; MFMA reads stride-1).
// B: glds from pre-swizzled W1e (1KB contiguous per instr).
#define BM 128
#define BN 128
#define BK 32

__global__ __launch_bounds__(256, 2) void k_energy(const float* __restrict__ enc,
                                                   const unsigned short* __restrict__ W1e,
                                                   const float* __restrict__ sp,
                                                   const float* __restrict__ W2,
                                                   float* __restrict__ logits) {
    __shared__ unsigned short As[BM * BK];   // 8 KB, 8 regions of 512 shorts
    __shared__ unsigned short Bs[BN * BK];   // 8 KB
    int bid = blockIdx.x;
    int c8  = bid & 7;                // XCD id (round-robin dispatch)
    int jj  = bid >> 3;
    int mT  = c8 * 32 + (jj >> 3);    // same-mT blocks share c8 -> same XCD L2
    int nT  = jj & 7;
    int m0  = mT * BM, n0 = nT * BN;
    int tid  = threadIdx.x;
    int lane = tid & 63, wave = tid >> 6;
    int wm   = (wave >> 1) << 6;
    int wn   = (wave & 1) << 6;

    // ---- A staging: 2 threads per row, 16 fp32 each ----
    int arow = tid >> 1;              // 0..127
    int kseg = (tid & 1) << 4;        // 0 or 16
    const float* gA = enc + (size_t)(m0 + arow) * H2 + kseg;
    int rg = arow >> 4;               // A region 0..7
    int L0 = ((kseg >> 3) << 4) | (arow & 15);    // chunk for ksub [kseg,kseg+8)
    unsigned short* wA0 = As + rg * 512 + L0 * 8;
    unsigned short* wA1 = wA0 + 128;  // chunk L0+16 (ksub +8), 256 B further

    // ---- B staging via glds: wave stages regions {2w, 2w+1} ----
    int rgb0 = wave * 2, rgb1 = wave * 2 + 1;
    const unsigned short* gB0 = W1e + ((size_t)(nT * 8 + rgb0) * 32) * 512 + lane * 8;
    const unsigned short* gB1 = W1e + ((size_t)(nT * 8 + rgb1) * 32) * 512 + lane * 8;
    unsigned short* lB0 = Bs + rgb0 * 512;   // wave-uniform LDS bases
    unsigned short* lB1 = Bs + rgb1 * 512;

    f32x4 acc[4][4];
    #pragma unroll
    for (int mi = 0; mi < 4; ++mi)
        #pragma unroll
        for (int ni = 0; ni < 4; ++ni)
            acc[mi][ni] = (f32x4){0.f, 0.f, 0.f, 0.f};

    int ablk = wm >> 4;               // first A region this wave consumes
    int bblk = wn >> 4;
    const unsigned short* afb = As + ablk * 512 + lane * 8;
    const unsigned short* bfb = Bs + bblk * 512 + lane * 8;

    for (int k0 = 0; k0 < H2; k0 += BK) {
        // A: global fp32 -> registers -> bf16 (issued before barrier, overlaps MFMA)
        float4 a0 = *(const float4*)(gA + k0);
        float4 a1 = *(const float4*)(gA + k0 + 4);
        float4 a2 = *(const float4*)(gA + k0 + 8);
        float4 a3 = *(const float4*)(gA + k0 + 12);
        uint4 p0, p1;
        p0.x = pack2_bf16(a0.x, a0.y); p0.y = pack2_bf16(a0.z, a0.w);
        p0.z = pack2_bf16(a1.x, a1.y); p0.w = pack2_bf16(a1.z, a1.w);
        p1.x = pack2_bf16(a2.x, a2.y); p1.y = pack2_bf16(a2.z, a2.w);
        p1.z = pack2_bf16(a3.x, a3.y); p1.w = pack2_bf16(a3.z, a3.w);
        __syncthreads();                       // prev iter's LDS reads retired
        *(uint4*)wA0 = p0;                     // ds_write_b128 x2, 2-way = free
        *(uint4*)wA1 = p1;
        gl_lds16(gB0 + k0 * 16, lB0);          // swizzled: +512 shorts per BK
        gl_lds16(gB1 + k0 * 16, lB1);
        __syncthreads();                       // lgkm+vm drain -> tiles visible
        short8 af[4], bf[4];
        #pragma unroll
        for (int i = 0; i < 4; ++i) {
            af[i] = *(const short8*)(afb + i * 512);
            bf[i] = *(const short8*)(bfb + i * 512);
        }
        #pragma unroll
        for (int mi = 0; mi < 4; ++mi)
            #pragma unroll
            for (int ni = 0; ni < 4; ++ni)
                acc[mi][ni] = __builtin_amdgcn_mfma_f32_16x16x32_bf16(af[mi], bf[ni], acc[mi][ni], 0, 0, 0);
    }

    // Epilogue: tanh + W2 dot, quad-shuffle reduce, atomic into logits[b][s]
    int c    = lane & 15;
    int quad = lane >> 4;
    float w2v[4];
    int   hcol[4];
    #pragma unroll
    for (int ni = 0; ni < 4; ++ni) {
        hcol[ni] = n0 + wn + ni * 16 + c;
        w2v[ni]  = W2[hcol[ni]];
    }
    #pragma unroll
    for (int mi = 0; mi < 4; ++mi) {
        #pragma unroll
        for (int i = 0; i < 4; ++i) {
            int m = m0 + wm + mi * 16 + quad * 4 + i;
            int b = m & 63;
            const float* sprow = sp + ((size_t)b << 10);
            float t = 0.f;
            #pragma unroll
            for (int ni = 0; ni < 4; ++ni) {
                float e = acc[mi][ni][i] + sprow[hcol[ni]];
                t = fmaf(fast_tanh(e), w2v[ni], t);
            }
            t += __shfl_xor(t, 1);
            t += __shfl_xor(t, 2);
            t += __shfl_xor(t, 4);
            t += __shfl_xor(t, 8);
            if (c == 0) atomicAdd(logits + (size_t)b * 512 + (m >> 6), t);
        }
    }
}

// ------------------------------------------------------------------
// k_softmax: softmax over s per b; also zeroes ctx (runs before k_context).
__global__ __launch_bounds__(256) void k_softmax(const float* __restrict__ logits,
                                                 float* __restrict__ alpha,
                                                 float* __restrict__ ctx) {
    int b = blockIdx.x;
    int tid = threadIdx.x;
    int lane = tid & 63, wave = tid >> 6;
    #pragma unroll
    for (int j = 0; j < 4; ++j)
        ctx[((size_t)b << 10) + j * 256 + tid] = 0.f;
    float v0 = logits[(size_t)b * 512 + tid];
    float v1 = logits[(size_t)b * 512 + 256 + tid];
    float mx = fmaxf(v0, v1);
    #pragma unroll
    for (int o = 32; o; o >>= 1) mx = fmaxf(mx, __shfl_xor(mx, o));
    __shared__ float redm[4];
    if (lane == 0) redm[wave] = mx;
    __syncthreads();
    mx = fmaxf(fmaxf(redm[0], redm[1]), fmaxf(redm[2], redm[3]));
    float e0 = __expf(v0 - mx), e1 = __expf(v1 - mx);
    float s = e0 + e1;
    #pragma unroll
    for (int o = 32; o; o >>= 1) s += __shfl_xor(s, o);
    __shared__ float reds[4];
    if (lane == 0) reds[wave] = s;
    __syncthreads();
    s = reds[0] + reds[1] + reds[2] + reds[3];
    float inv = 1.0f / s;
    alpha[(size_t)b * 512 + tid]       = e0 * inv;
    alpha[(size_t)b * 512 + 256 + tid] = e1 * inv;
}

// ------------------------------------------------------------------
// k_context: context[b][h] = sum_s alpha[b][s] * enc[s][b][h], fp32.
__global__ __launch_bounds__(256) void k_context(const float* __restrict__ enc,
                                                 const float* __restrict__ alpha,
                                                 float* __restrict__ ctx) {
    int b  = blockIdx.x & 63;
    int sc = blockIdx.x >> 6;
    int h  = threadIdx.x << 2;
    float4 acc = make_float4(0.f, 0.f, 0.f, 0.f);
    int sbase = sc * 64;
    #pragma unroll 4
    for (int si = 0; si < 64; ++si) {
        int s = sbase + si;
        float a = alpha[(size_t)b * 512 + s];
        float4 e = *(const float4*)(enc + (((size_t)s * 64 + b) << 10) + h);
        acc.x = fmaf(a, e.x, acc.x);
        acc.y = fmaf(a, e.y, acc.y);
        acc.z = fmaf(a, e.z, acc.z);
        acc.w = fmaf(a, e.w, acc.w);
    }
    float* dst = ctx + ((size_t)b << 10) + h;
    atomicAdd(dst + 0, acc.x);
    atomicAdd(dst + 1, acc.y);
    atomicAdd(dst + 2, acc.z);
    atomicAdd(dst + 3, acc.w);
}

// ------------------------------------------------------------------
extern "C" void kernel_launch(void* const* d_in, const int* in_sizes, int n_in,
                              void* d_out, int out_size, void* d_ws, size_t ws_size,
                              hipStream_t stream) {
    const float* state = (const float*)d_in[0];   // (2, 64, 1024)
    const float* enc   = (const float*)d_in[1];   // (512, 64, 1024)
    const float* W1    = (const float*)d_in[2];   // (1024, 3072)
    const float* b1    = (const float*)d_in[3];   // (1024,)
    const float* W2    = (const float*)d_in[4];   // (1, 1024)
    // d_in[5] = b2: dropped — softmax is shift-invariant.

    float* ctx   = (float*)d_out;                 // (1,64,1024) = 65536 fp32
    float* alpha = (float*)d_out + 65536;         // (64,1,512)  = 32768 fp32

    char* ws = (char*)d_ws;
    unsigned short* W1e    = (unsigned short*)(ws);             // 2 MB bf16 swizzled
    float*          sp     = (float*)(ws + 2097152);            // 256 KB [b][h]
    float*          logits = (float*)(ws + 2097152 + 262144);   // 128 KB [b][s]

    k_setup<<<704, 256, 0, stream>>>(W1, b1, state, W1e, logits, sp);
    k_energy<<<M_TOTAL / BM * (H2 / BN), 256, 0, stream>>>(enc, W1e, sp, W2, logits);
    k_softmax<<<64, 256, 0, stream>>>(logits, alpha, ctx);
    k_context<<<512, 256, 0, stream>>>(enc, alpha, ctx);
}